// Round 12
// baseline (167.141 us; speedup 1.0000x reference)
//
#include <hip/hip_runtime.h>
#include <math.h>

#define IN_NODES  4096
#define OUT_NODES 1024
#define ROW_ELEMS 16384          // elems per in-node row (1024*16)
#define ROW_C4    4096           // 4-elem chunks per row
#define ROW_U4    2048           // uint4 (8xbf16) chunks per row
#define G_UNI     512            // blocks for uniform pass (512 thr, 2/CU)
#define NG        256            // blocks for softmax passes (1024 thr)
#define PB        16             // rows per soft block (4096/256)
#define PBU       8              // rows per uniform block (4096/512)

typedef unsigned short u16;
typedef unsigned int   u32;

__device__ __forceinline__ float dot4(const float4 a, const float4 b) {
    return a.x*b.x + a.y*b.y + a.z*b.z + a.w*b.w;
}
__device__ __forceinline__ void fma4(float4& a, const float c, const float4 u) {
    a.x += c*u.x; a.y += c*u.y; a.z += c*u.z; a.w += c*u.w;
}
__device__ __forceinline__ void add4(float4& a, const float4 u) {
    a.x += u.x; a.y += u.y; a.z += u.z; a.w += u.w;
}
__device__ __forceinline__ float b2f1(u16 u) {
    return __uint_as_float(((u32)u) << 16);
}
__device__ __forceinline__ u16 f2b(float x) {            // RNE f32->bf16
    u32 b = __float_as_uint(x);
    return (u16)((b + 0x7FFFu + ((b >> 16) & 1u)) >> 16);
}
__device__ __forceinline__ ushort4 f2b4(float4 v) {
    ushort4 r; r.x = f2b(v.x); r.y = f2b(v.y); r.z = f2b(v.z); r.w = f2b(v.w);
    return r;
}
// uint4 = 8 bf16 (memory order) -> two float4
__device__ __forceinline__ void unpack8(const uint4 w, float4& lo, float4& hi) {
    lo.x = __uint_as_float(w.x << 16);
    lo.y = __uint_as_float(w.x & 0xFFFF0000u);
    lo.z = __uint_as_float(w.y << 16);
    lo.w = __uint_as_float(w.y & 0xFFFF0000u);
    hi.x = __uint_as_float(w.z << 16);
    hi.y = __uint_as_float(w.z & 0xFFFF0000u);
    hi.z = __uint_as_float(w.w << 16);
    hi.w = __uint_as_float(w.w & 0xFFFF0000u);
}

// ---------------------------------------------------------------------------
// K0: uniform pass (c = 1/1024) + bf16 copy of u_hat.
// 512 blocks x 512 thr (2 blocks/CU, ~90 VGPR, no barriers): deeper
// store/load overlap on the 3-stream pattern than the old 1-block/CU shape.
// Thread owns chunks c = j*512 + t (j=0..7): 1KB contiguous per wave instr.
// ---------------------------------------------------------------------------
__global__ __launch_bounds__(512, 4) void k_uniform(const float* __restrict__ uh,
                                                    u16* __restrict__ uh2,
                                                    u16* __restrict__ part) {
    const int t = threadIdx.x;

    float4 acc[8];
    #pragma unroll
    for (int j = 0; j < 8; ++j) acc[j] = make_float4(0.f, 0.f, 0.f, 0.f);

    const float4* p = reinterpret_cast<const float4*>(uh)
                    + (size_t)blockIdx.x * PBU * ROW_C4;
    ushort4* q = reinterpret_cast<ushort4*>(uh2)
               + (size_t)blockIdx.x * PBU * ROW_C4;

    for (int g = 0; g < PBU; ++g) {
        float4 u[8];
        #pragma unroll
        for (int j = 0; j < 8; ++j) u[j] = p[j * 512 + t];
        #pragma unroll
        for (int j = 0; j < 8; ++j) { add4(acc[j], u[j]); q[j * 512 + t] = f2b4(u[j]); }
        p += ROW_C4; q += ROW_C4;
    }

    const float c = 1.0f / OUT_NODES;
    ushort4* sp = reinterpret_cast<ushort4*>(part) + (size_t)blockIdx.x * ROW_C4;
    #pragma unroll
    for (int j = 0; j < 8; ++j) {
        acc[j].x *= c; acc[j].y *= c; acc[j].z *= c; acc[j].w *= c;
        sp[j * 512 + t] = f2b4(acc[j]);
    }
}

// ---------------------------------------------------------------------------
// K_soft: softmax pass over the bf16 copy. 256 blocks x 1024 thr. Identical
// to the proven R11 kernel EXCEPT the denominator reduce is single-barrier:
// after red16[] is written, EVERY lane reads red16[lane&15] and does a
// 4-step shfl_xor tree (offsets 1,2,4,8) -> full block sum in all lanes.
// Removes the second __syncthreads and the serial wave0 stage (8 of 16
// barriers per block).
// ---------------------------------------------------------------------------
__global__ __launch_bounds__(1024, 4) void k_soft(const u16* __restrict__ uh2,
                                                  const float* __restrict__ V,
                                                  u16* __restrict__ part) {
    const int t    = threadIdx.x;
    const int wave = t >> 6;
    const int lane = t & 63;
    const int u0   = (wave << 7) + lane;      // first uint4 unit (second +64)

    __shared__ float2 red16[16];

    float4 v[4];
    {
        const float4* vp = reinterpret_cast<const float4*>(V);
        v[0] = vp[2 * u0];          v[1] = vp[2 * u0 + 1];
        v[2] = vp[2 * (u0 + 64)];   v[3] = vp[2 * (u0 + 64) + 1];
    }

    float4 acc[4];
    #pragma unroll
    for (int j = 0; j < 4; ++j) acc[j] = make_float4(0.f, 0.f, 0.f, 0.f);

    const uint4* p = reinterpret_cast<const uint4*>(uh2)
                   + (size_t)blockIdx.x * PB * ROW_U4 + u0;

    // cur = rows g, g+1 (units u0, u0+64 each)
    uint4 cur[4];
    cur[0] = p[0];      cur[1] = p[64];
    cur[2] = p[ROW_U4]; cur[3] = p[ROW_U4 + 64];

    for (int g = 0; g < PB; g += 2) {
        uint4 nxt[4];
        const uint4* pn = p + 2 * ROW_U4;
        if (g + 2 < PB) {
            nxt[0] = pn[0];      nxt[1] = pn[64];
            nxt[2] = pn[ROW_U4]; nxt[3] = pn[ROW_U4 + 64];
        }

        // dots (row a: cur[0],cur[1]; row b: cur[2],cur[3])
        float d[4];
        #pragma unroll
        for (int j = 0; j < 4; ++j) {
            float4 lo, hi;
            unpack8(cur[j], lo, hi);
            d[j] = dot4(lo, v[(j & 1) * 2]) + dot4(hi, v[(j & 1) * 2 + 1]);
        }
        #pragma unroll
        for (int j = 0; j < 4; ++j) d[j] += __shfl_xor(d[j], 1);

        float e[4];
        #pragma unroll
        for (int j = 0; j < 4; ++j) e[j] = __expf(d[j]);

        float ea = e[0] + e[1];       // row a partial denom (each o counted 2x)
        float eb = e[2] + e[3];       // row b
        #pragma unroll
        for (int off = 32; off; off >>= 1) {
            ea += __shfl_xor(ea, off);
            eb += __shfl_xor(eb, off);
        }
        if (lane == 0) red16[wave] = make_float2(ea, eb);
        __syncthreads();
        // all-wave redundant final reduce (no second barrier, no serial wave0)
        float2 qv = red16[lane & 15];
        #pragma unroll
        for (int off = 1; off < 16; off <<= 1) {
            qv.x += __shfl_xor(qv.x, off);
            qv.y += __shfl_xor(qv.y, off);
        }
        const float inva = 2.0f / qv.x;
        const float invb = 2.0f / qv.y;
        __syncthreads();   // protect red16 from next iteration's overwrite

        // FMA phase: recompute unpack (keeps live state small)
        #pragma unroll
        for (int j = 0; j < 4; ++j) {
            float4 lo, hi;
            unpack8(cur[j], lo, hi);
            const float c = e[j] * ((j < 2) ? inva : invb);
            fma4(acc[(j & 1) * 2],     c, lo);
            fma4(acc[(j & 1) * 2 + 1], c, hi);
        }

        #pragma unroll
        for (int j = 0; j < 4; ++j) cur[j] = nxt[j];
        p = pn;
    }

    ushort4* sp = reinterpret_cast<ushort4*>(part) + (size_t)blockIdx.x * ROW_C4;
    sp[2 * u0]            = f2b4(acc[0]);
    sp[2 * u0 + 1]        = f2b4(acc[1]);
    sp[2 * (u0 + 64)]     = f2b4(acc[2]);
    sp[2 * (u0 + 64) + 1] = f2b4(acc[3]);
}

// ---------------------------------------------------------------------------
// Reduce bf16 partials -> s (f32), squash -> v, out, cumulative V.
// ---------------------------------------------------------------------------
__global__ __launch_bounds__(256) void k_reduce(const u16* __restrict__ part,
                                                float* __restrict__ V,
                                                float* __restrict__ out,
                                                int G, int first) {
    const int t    = threadIdx.x;
    const int gidx = blockIdx.x * 64 + (t >> 2);   // o*16 + f
    const int q    = t & 3;
    const u16* p = part + gidx;
    float a0 = 0.f, a1 = 0.f;
    int b = q;
    for (; b + 4 < G; b += 8) {
        a0 += b2f1(p[(size_t)(b    ) * ROW_ELEMS]);
        a1 += b2f1(p[(size_t)(b + 4) * ROW_ELEMS]);
    }
    for (; b < G; b += 4) a0 += b2f1(p[(size_t)b * ROW_ELEMS]);
    float s = a0 + a1;
    s += __shfl_xor(s, 1);
    s += __shfl_xor(s, 2);

    float sq = s * s;
    sq += __shfl_xor(sq, 4);
    sq += __shfl_xor(sq, 8);
    sq += __shfl_xor(sq, 16);
    sq += __shfl_xor(sq, 32);

    const float scale = sq / ((1.0f + sq) * sqrtf(sq));
    const float v = s * scale;

    out[gidx] = v;
    V[gidx]   = first ? v : (V[gidx] + v);
}

// ===========================================================================
// f32-input fallback (only if workspace is unexpectedly small).
// ===========================================================================
__global__ __launch_bounds__(1024, 4) void fb_uniform(const float* __restrict__ uh,
                                                      u16* __restrict__ part,
                                                      int per_block) {
    const int t  = threadIdx.x;
    const int c0 = ((t >> 6) << 8) + (t & 63);
    float4 acc[4];
    #pragma unroll
    for (int j = 0; j < 4; ++j) acc[j] = make_float4(0.f, 0.f, 0.f, 0.f);
    const float4* p = reinterpret_cast<const float4*>(uh)
                    + (size_t)blockIdx.x * per_block * ROW_C4 + c0;
    for (int g = 0; g < per_block; ++g) {
        #pragma unroll
        for (int j = 0; j < 4; ++j) add4(acc[j], p[j * 64]);
        p += ROW_C4;
    }
    const float c = 1.0f / OUT_NODES;
    ushort4* sp = reinterpret_cast<ushort4*>(part) + (size_t)blockIdx.x * ROW_C4 + c0;
    #pragma unroll
    for (int j = 0; j < 4; ++j) {
        acc[j].x *= c; acc[j].y *= c; acc[j].z *= c; acc[j].w *= c;
        sp[j * 64] = f2b4(acc[j]);
    }
}

__global__ __launch_bounds__(1024, 4) void fb_soft(const float* __restrict__ uh,
                                                   const float* __restrict__ V,
                                                   u16* __restrict__ part,
                                                   int per_block) {
    const int t    = threadIdx.x;
    const int wave = t >> 6;
    const int lane = t & 63;
    const int c0   = (wave << 8) + lane;
    __shared__ float red16[16];

    float4 v[4];
    const float4* vp = reinterpret_cast<const float4*>(V) + c0;
    #pragma unroll
    for (int j = 0; j < 4; ++j) v[j] = vp[j * 64];

    float4 acc[4];
    #pragma unroll
    for (int j = 0; j < 4; ++j) acc[j] = make_float4(0.f, 0.f, 0.f, 0.f);

    const float4* p = reinterpret_cast<const float4*>(uh)
                    + (size_t)blockIdx.x * per_block * ROW_C4 + c0;
    for (int g = 0; g < per_block; ++g) {
        float4 u[4];
        #pragma unroll
        for (int j = 0; j < 4; ++j) u[j] = p[j * 64];
        float d[4];
        #pragma unroll
        for (int j = 0; j < 4; ++j) d[j] = dot4(u[j], v[j]);
        #pragma unroll
        for (int j = 0; j < 4; ++j) {
            d[j] += __shfl_xor(d[j], 1);
            d[j] += __shfl_xor(d[j], 2);
        }
        float e[4];
        float etot = 0.f;
        #pragma unroll
        for (int j = 0; j < 4; ++j) { e[j] = __expf(d[j]); etot += e[j]; }
        #pragma unroll
        for (int off = 32; off; off >>= 1) etot += __shfl_xor(etot, off);
        if (lane == 0) red16[wave] = etot;
        __syncthreads();
        float s = red16[lane & 15];
        #pragma unroll
        for (int off = 1; off < 16; off <<= 1) s += __shfl_xor(s, off);
        const float inv = 4.0f / s;
        __syncthreads();
        #pragma unroll
        for (int j = 0; j < 4; ++j) fma4(acc[j], e[j] * inv, u[j]);
        p += ROW_C4;
    }
    ushort4* sp = reinterpret_cast<ushort4*>(part) + (size_t)blockIdx.x * ROW_C4 + c0;
    #pragma unroll
    for (int j = 0; j < 4; ++j) sp[j * 64] = f2b4(acc[j]);
}

// ---------------------------------------------------------------------------
extern "C" void kernel_launch(void* const* d_in, const int* in_sizes, int n_in,
                              void* d_out, int out_size, void* d_ws, size_t ws_size,
                              hipStream_t stream) {
    const float* uh  = (const float*)d_in[0];
    float*       out = (float*)d_out;

    // ws layout: V (64 KB f32) | part (512 * 32 KB bf16 = 16 MB) | uh2 (128 MB)
    char*  ws   = (char*)d_ws;
    float* V    = (float*)ws;
    u16*   part = (u16*)(ws + 65536);
    u16*   uh2  = (u16*)(ws + 65536 + (size_t)G_UNI * ROW_ELEMS * 2);

    const size_t need = 65536ull + (size_t)G_UNI * ROW_ELEMS * 2ull
                      + (size_t)IN_NODES * ROW_ELEMS * 2ull;

    if (ws_size >= need) {
        k_uniform<<<G_UNI, 512, 0, stream>>>(uh, uh2, part);
        k_reduce<<<256, 256, 0, stream>>>(part, V, out, G_UNI, 1);
        for (int it = 1; it < 3; ++it) {
            k_soft<<<NG, 1024, 0, stream>>>(uh2, V, part);
            k_reduce<<<256, 256, 0, stream>>>(part, V, out, NG, 0);
        }
    } else {
        int G2 = 256;
        while (G2 > 4 && ws_size < 65536ull + 32768ull * (size_t)G2) G2 >>= 1;
        const int per_block = IN_NODES / G2;
        fb_uniform<<<G2, 1024, 0, stream>>>(uh, part, per_block);
        k_reduce<<<256, 256, 0, stream>>>(part, V, out, G2, 1);
        for (int it = 1; it < 3; ++it) {
            fb_soft<<<G2, 1024, 0, stream>>>(uh, V, part, per_block);
            k_reduce<<<256, 256, 0, stream>>>(part, V, out, G2, 0);
        }
    }
}

// Round 13
// 158.076 us; speedup vs baseline: 1.0573x; 1.0573x over previous
//
#include <hip/hip_runtime.h>
#include <math.h>

#define IN_NODES  4096
#define OUT_NODES 1024
#define ROW_ELEMS 16384          // elems per in-node row (1024*16)
#define ROW_C4    4096           // 4-elem chunks per row
#define ROW_U4    2048           // uint4 (8xbf16) chunks per row
#define NG        256            // grid
#define PB        16             // rows per block (4096/256)

typedef unsigned short u16;
typedef unsigned int   u32;

__device__ __forceinline__ float dot4(const float4 a, const float4 b) {
    return a.x*b.x + a.y*b.y + a.z*b.z + a.w*b.w;
}
__device__ __forceinline__ void fma4(float4& a, const float c, const float4 u) {
    a.x += c*u.x; a.y += c*u.y; a.z += c*u.z; a.w += c*u.w;
}
__device__ __forceinline__ void add4(float4& a, const float4 u) {
    a.x += u.x; a.y += u.y; a.z += u.z; a.w += u.w;
}
__device__ __forceinline__ float b2f1(u16 u) {
    return __uint_as_float(((u32)u) << 16);
}
__device__ __forceinline__ u16 f2b(float x) {            // RNE f32->bf16
    u32 b = __float_as_uint(x);
    return (u16)((b + 0x7FFFu + ((b >> 16) & 1u)) >> 16);
}
__device__ __forceinline__ ushort4 f2b4(float4 v) {
    ushort4 r; r.x = f2b(v.x); r.y = f2b(v.y); r.z = f2b(v.z); r.w = f2b(v.w);
    return r;
}
// uint4 = 8 bf16 (memory order) -> two float4
__device__ __forceinline__ void unpack8(const uint4 w, float4& lo, float4& hi) {
    lo.x = __uint_as_float(w.x << 16);
    lo.y = __uint_as_float(w.x & 0xFFFF0000u);
    lo.z = __uint_as_float(w.y << 16);
    lo.w = __uint_as_float(w.y & 0xFFFF0000u);
    hi.x = __uint_as_float(w.z << 16);
    hi.y = __uint_as_float(w.z & 0xFFFF0000u);
    hi.z = __uint_as_float(w.w << 16);
    hi.w = __uint_as_float(w.w & 0xFFFF0000u);
}

// ---------------------------------------------------------------------------
// K0: uniform pass (c = 1/1024) + bf16 copy of u_hat. 256 blocks x 1024 thr,
// no barriers, fully coalesced. (R11 exact — session best 158.2 us.)
// ---------------------------------------------------------------------------
__global__ __launch_bounds__(1024, 4) void k_uniform(const float* __restrict__ uh,
                                                     u16* __restrict__ uh2,
                                                     u16* __restrict__ part) {
    const int t    = threadIdx.x;
    const int wave = t >> 6;
    const int lane = t & 63;
    const int c0   = (wave << 8) + lane;

    float4 acc[4];
    #pragma unroll
    for (int j = 0; j < 4; ++j) acc[j] = make_float4(0.f, 0.f, 0.f, 0.f);

    const float4* p = reinterpret_cast<const float4*>(uh)
                    + (size_t)blockIdx.x * PB * ROW_C4 + c0;
    ushort4* q = reinterpret_cast<ushort4*>(uh2)
               + (size_t)blockIdx.x * PB * ROW_C4 + c0;

    for (int g = 0; g < PB; ++g) {
        float4 u[4];
        #pragma unroll
        for (int j = 0; j < 4; ++j) u[j] = p[j * 64];
        #pragma unroll
        for (int j = 0; j < 4; ++j) { add4(acc[j], u[j]); q[j * 64] = f2b4(u[j]); }
        p += ROW_C4; q += ROW_C4;
    }

    const float c = 1.0f / OUT_NODES;
    ushort4* sp = reinterpret_cast<ushort4*>(part) + (size_t)blockIdx.x * ROW_C4 + c0;
    #pragma unroll
    for (int j = 0; j < 4; ++j) {
        acc[j].x *= c; acc[j].y *= c; acc[j].z *= c; acc[j].w *= c;
        sp[j * 64] = f2b4(acc[j]);
    }
}

// ---------------------------------------------------------------------------
// K_soft: softmax pass over the bf16 copy. (R11 exact.)
// ---------------------------------------------------------------------------
__global__ __launch_bounds__(1024, 4) void k_soft(const u16* __restrict__ uh2,
                                                  const float* __restrict__ V,
                                                  u16* __restrict__ part) {
    const int t    = threadIdx.x;
    const int wave = t >> 6;
    const int lane = t & 63;
    const int u0   = (wave << 7) + lane;      // first uint4 unit (second +64)

    __shared__ float2 red16[16];
    __shared__ float2 redS;

    float4 v[4];
    {
        const float4* vp = reinterpret_cast<const float4*>(V);
        v[0] = vp[2 * u0];          v[1] = vp[2 * u0 + 1];
        v[2] = vp[2 * (u0 + 64)];   v[3] = vp[2 * (u0 + 64) + 1];
    }

    float4 acc[4];
    #pragma unroll
    for (int j = 0; j < 4; ++j) acc[j] = make_float4(0.f, 0.f, 0.f, 0.f);

    const uint4* p = reinterpret_cast<const uint4*>(uh2)
                   + (size_t)blockIdx.x * PB * ROW_U4 + u0;

    // cur = rows g, g+1 (units u0, u0+64 each)
    uint4 cur[4];
    cur[0] = p[0];      cur[1] = p[64];
    cur[2] = p[ROW_U4]; cur[3] = p[ROW_U4 + 64];

    for (int g = 0; g < PB; g += 2) {
        uint4 nxt[4];
        const uint4* pn = p + 2 * ROW_U4;
        if (g + 2 < PB) {
            nxt[0] = pn[0];      nxt[1] = pn[64];
            nxt[2] = pn[ROW_U4]; nxt[3] = pn[ROW_U4 + 64];
        }

        // dots (row a: cur[0],cur[1]; row b: cur[2],cur[3])
        float d[4];
        #pragma unroll
        for (int j = 0; j < 4; ++j) {
            float4 lo, hi;
            unpack8(cur[j], lo, hi);
            d[j] = dot4(lo, v[(j & 1) * 2]) + dot4(hi, v[(j & 1) * 2 + 1]);
        }
        #pragma unroll
        for (int j = 0; j < 4; ++j) d[j] += __shfl_xor(d[j], 1);

        float e[4];
        #pragma unroll
        for (int j = 0; j < 4; ++j) e[j] = __expf(d[j]);

        float ea = e[0] + e[1];       // row a partial denom (each o counted 2x)
        float eb = e[2] + e[3];       // row b
        #pragma unroll
        for (int off = 32; off; off >>= 1) {
            ea += __shfl_xor(ea, off);
            eb += __shfl_xor(eb, off);
        }
        if (lane == 0) red16[wave] = make_float2(ea, eb);
        __syncthreads();
        if (wave == 0) {
            float2 qv = (lane < 16) ? red16[lane] : make_float2(0.f, 0.f);
            #pragma unroll
            for (int off = 8; off; off >>= 1) {
                qv.x += __shfl_xor(qv.x, off);
                qv.y += __shfl_xor(qv.y, off);
            }
            if (lane == 0) redS = qv;
        }
        __syncthreads();
        const float inva = 2.0f / redS.x;
        const float invb = 2.0f / redS.y;

        // FMA phase: recompute unpack (keeps live state small)
        #pragma unroll
        for (int j = 0; j < 4; ++j) {
            float4 lo, hi;
            unpack8(cur[j], lo, hi);
            const float c = e[j] * ((j < 2) ? inva : invb);
            fma4(acc[(j & 1) * 2],     c, lo);
            fma4(acc[(j & 1) * 2 + 1], c, hi);
        }

        #pragma unroll
        for (int j = 0; j < 4; ++j) cur[j] = nxt[j];
        p = pn;
    }

    ushort4* sp = reinterpret_cast<ushort4*>(part) + (size_t)blockIdx.x * ROW_C4;
    sp[2 * u0]            = f2b4(acc[0]);
    sp[2 * u0 + 1]        = f2b4(acc[1]);
    sp[2 * (u0 + 64)]     = f2b4(acc[2]);
    sp[2 * (u0 + 64) + 1] = f2b4(acc[3]);
}

// ---------------------------------------------------------------------------
// Reduce bf16 partials -> s (f32), squash -> v, out, cumulative V. (R11 exact.)
// ---------------------------------------------------------------------------
__global__ __launch_bounds__(256) void k_reduce(const u16* __restrict__ part,
                                                float* __restrict__ V,
                                                float* __restrict__ out,
                                                int G, int first) {
    const int t    = threadIdx.x;
    const int gidx = blockIdx.x * 64 + (t >> 2);   // o*16 + f
    const int q    = t & 3;
    const u16* p = part + gidx;
    float a0 = 0.f, a1 = 0.f;
    int b = q;
    for (; b + 4 < G; b += 8) {
        a0 += b2f1(p[(size_t)(b    ) * ROW_ELEMS]);
        a1 += b2f1(p[(size_t)(b + 4) * ROW_ELEMS]);
    }
    for (; b < G; b += 4) a0 += b2f1(p[(size_t)b * ROW_ELEMS]);
    float s = a0 + a1;
    s += __shfl_xor(s, 1);
    s += __shfl_xor(s, 2);

    float sq = s * s;
    sq += __shfl_xor(sq, 4);
    sq += __shfl_xor(sq, 8);
    sq += __shfl_xor(sq, 16);
    sq += __shfl_xor(sq, 32);

    const float scale = sq / ((1.0f + sq) * sqrtf(sq));
    const float v = s * scale;

    out[gidx] = v;
    V[gidx]   = first ? v : (V[gidx] + v);
}

// ===========================================================================
// f32-input fallback (only if workspace is unexpectedly small).
// ===========================================================================
__global__ __launch_bounds__(1024, 4) void fb_uniform(const float* __restrict__ uh,
                                                      u16* __restrict__ part,
                                                      int per_block) {
    const int t  = threadIdx.x;
    const int c0 = ((t >> 6) << 8) + (t & 63);
    float4 acc[4];
    #pragma unroll
    for (int j = 0; j < 4; ++j) acc[j] = make_float4(0.f, 0.f, 0.f, 0.f);
    const float4* p = reinterpret_cast<const float4*>(uh)
                    + (size_t)blockIdx.x * per_block * ROW_C4 + c0;
    for (int g = 0; g < per_block; ++g) {
        #pragma unroll
        for (int j = 0; j < 4; ++j) add4(acc[j], p[j * 64]);
        p += ROW_C4;
    }
    const float c = 1.0f / OUT_NODES;
    ushort4* sp = reinterpret_cast<ushort4*>(part) + (size_t)blockIdx.x * ROW_C4 + c0;
    #pragma unroll
    for (int j = 0; j < 4; ++j) {
        acc[j].x *= c; acc[j].y *= c; acc[j].z *= c; acc[j].w *= c;
        sp[j * 64] = f2b4(acc[j]);
    }
}

__global__ __launch_bounds__(1024, 4) void fb_soft(const float* __restrict__ uh,
                                                   const float* __restrict__ V,
                                                   u16* __restrict__ part,
                                                   int per_block) {
    const int t    = threadIdx.x;
    const int wave = t >> 6;
    const int lane = t & 63;
    const int c0   = (wave << 8) + lane;
    __shared__ float red16[16];
    __shared__ float redS;

    float4 v[4];
    const float4* vp = reinterpret_cast<const float4*>(V) + c0;
    #pragma unroll
    for (int j = 0; j < 4; ++j) v[j] = vp[j * 64];

    float4 acc[4];
    #pragma unroll
    for (int j = 0; j < 4; ++j) acc[j] = make_float4(0.f, 0.f, 0.f, 0.f);

    const float4* p = reinterpret_cast<const float4*>(uh)
                    + (size_t)blockIdx.x * per_block * ROW_C4 + c0;
    for (int g = 0; g < per_block; ++g) {
        float4 u[4];
        #pragma unroll
        for (int j = 0; j < 4; ++j) u[j] = p[j * 64];
        float d[4];
        #pragma unroll
        for (int j = 0; j < 4; ++j) d[j] = dot4(u[j], v[j]);
        #pragma unroll
        for (int j = 0; j < 4; ++j) {
            d[j] += __shfl_xor(d[j], 1);
            d[j] += __shfl_xor(d[j], 2);
        }
        float e[4];
        float etot = 0.f;
        #pragma unroll
        for (int j = 0; j < 4; ++j) { e[j] = __expf(d[j]); etot += e[j]; }
        #pragma unroll
        for (int off = 32; off; off >>= 1) etot += __shfl_xor(etot, off);
        if (lane == 0) red16[wave] = etot;
        __syncthreads();
        if (wave == 0) {
            float s = (lane < 16) ? red16[lane] : 0.f;
            #pragma unroll
            for (int off = 8; off; off >>= 1) s += __shfl_xor(s, off);
            if (lane == 0) redS = s;
        }
        __syncthreads();
        const float inv = 4.0f / redS;
        #pragma unroll
        for (int j = 0; j < 4; ++j) fma4(acc[j], e[j] * inv, u[j]);
        p += ROW_C4;
    }
    ushort4* sp = reinterpret_cast<ushort4*>(part) + (size_t)blockIdx.x * ROW_C4 + c0;
    #pragma unroll
    for (int j = 0; j < 4; ++j) sp[j * 64] = f2b4(acc[j]);
}

// ---------------------------------------------------------------------------
extern "C" void kernel_launch(void* const* d_in, const int* in_sizes, int n_in,
                              void* d_out, int out_size, void* d_ws, size_t ws_size,
                              hipStream_t stream) {
    const float* uh  = (const float*)d_in[0];
    float*       out = (float*)d_out;

    // ws layout: V (64 KB f32) | part (256 * 32 KB bf16 = 8 MB) | uh2 (128 MB)
    char*  ws   = (char*)d_ws;
    float* V    = (float*)ws;
    u16*   part = (u16*)(ws + 65536);
    u16*   uh2  = (u16*)(ws + 65536 + (size_t)NG * ROW_ELEMS * 2);

    const size_t need = 65536ull + (size_t)NG * ROW_ELEMS * 2ull
                      + (size_t)IN_NODES * ROW_ELEMS * 2ull;

    if (ws_size >= need) {
        k_uniform<<<NG, 1024, 0, stream>>>(uh, uh2, part);
        k_reduce<<<256, 256, 0, stream>>>(part, V, out, NG, 1);
        for (int it = 1; it < 3; ++it) {
            k_soft<<<NG, 1024, 0, stream>>>(uh2, V, part);
            k_reduce<<<256, 256, 0, stream>>>(part, V, out, NG, 0);
        }
    } else {
        int G2 = 256;
        while (G2 > 4 && ws_size < 65536ull + 32768ull * (size_t)G2) G2 >>= 1;
        const int per_block = IN_NODES / G2;
        fb_uniform<<<G2, 1024, 0, stream>>>(uh, part, per_block);
        k_reduce<<<256, 256, 0, stream>>>(part, V, out, G2, 1);
        for (int it = 1; it < 3; ++it) {
            fb_soft<<<G2, 1024, 0, stream>>>(uh, V, part, per_block);
            k_reduce<<<256, 256, 0, stream>>>(part, V, out, G2, 0);
        }
    }
}